// Round 1
// baseline (613.011 us; speedup 1.0000x reference)
//
#include <hip/hip_runtime.h>
#include <math.h>

typedef __attribute__((ext_vector_type(8))) __bf16 bf16x8;
typedef __attribute__((ext_vector_type(4))) float f32x4;

#define MFMA16(a, b, c) __builtin_amdgcn_mfma_f32_16x16x32_bf16((a), (b), (c), 0, 0, 0)

static constexpr int Bb  = 2;
static constexpr int Nn  = 2048;
static constexpr int Dd  = 2048;
static constexpr int Hh  = 8;
static constexpr int Gg  = 4;
static constexpr int Cc  = 64;    // head dim
static constexpr int KVW = 1024;  // 2*H*C

__device__ __forceinline__ unsigned short f2bf(float f) {
  unsigned int u = __float_as_uint(f);
  u += 0x7FFFu + ((u >> 16) & 1u);   // RNE
  return (unsigned short)(u >> 16);
}

// ---------------- fp32 -> bf16 convert (vectorized) ----------------
__global__ void xconv(const float* __restrict__ x, unsigned short* __restrict__ xb, int n4) {
  int i = blockIdx.x * blockDim.x + threadIdx.x;
  const int stride = gridDim.x * blockDim.x;
  for (; i < n4; i += stride) {
    float4 v = ((const float4*)x)[i];
    ushort4 o;
    o.x = f2bf(v.x); o.y = f2bf(v.y); o.z = f2bf(v.z); o.w = f2bf(v.w);
    ((ushort4*)xb)[i] = o;
  }
}

// ------- weight convert + transpose: W[K][N] fp32 -> Wt[N][K] bf16, scaled -------
__global__ void wconv(const float* __restrict__ W, unsigned short* __restrict__ Wt,
                      int K, int N, float scale) {
  __shared__ float t[32][33];
  const int n0 = blockIdx.x * 32, k0 = blockIdx.y * 32;
  for (int i = threadIdx.x; i < 1024; i += blockDim.x) {
    int r = i >> 5, c = i & 31;
    t[r][c] = W[(size_t)(k0 + r) * N + n0 + c];
  }
  __syncthreads();
  for (int i = threadIdx.x; i < 1024; i += blockDim.x) {
    int r = i >> 5, c = i & 31;
    Wt[(size_t)(n0 + r) * K + k0 + c] = f2bf(t[c][r] * scale);
  }
}

// ------- V transpose: kvb[b][s][512 + h*64 + c] -> vT[b][h][c][s] -------
__global__ void vtrans(const unsigned short* __restrict__ kvb, unsigned short* __restrict__ vT) {
  __shared__ unsigned short t[64][72];
  const int s0 = blockIdx.x * 64;
  const int b = blockIdx.y >> 3, h = blockIdx.y & 7;
  const unsigned short* src = kvb + ((size_t)b * Nn + s0) * KVW + Hh * Cc + h * Cc;
  for (int i = threadIdx.x; i < 4096; i += blockDim.x) {
    int s = i >> 6, c = i & 63;
    t[s][c] = src[(size_t)s * KVW + c];
  }
  __syncthreads();
  unsigned short* dst = vT + (size_t)(b * Hh + h) * Cc * Nn + s0;
  for (int i = threadIdx.x; i < 4096; i += blockDim.x) {
    int c = i >> 6, s = i & 63;
    dst[(size_t)c * Nn + s] = t[s][c];
  }
}

// ------- GEMM: C[M,N] = A[M,K] @ Bt[N,K]^T ; bf16 in, bf16 or (fp32+bias) out -------
// 128x128 tile, 4 waves (2x2), wave tile 64x64, BK=32, single-buffer LDS w/ reg prefetch.
template <bool OUTF32>
__global__ __launch_bounds__(256, 2)
void gemm_bt(const unsigned short* __restrict__ A, const unsigned short* __restrict__ Bt,
             unsigned short* __restrict__ Cb, float* __restrict__ Cf,
             const float* __restrict__ bias, int M, int N, int K) {
  __shared__ unsigned short As[128 * 40];  // +8 pad per row (bank spread)
  __shared__ unsigned short Bs[128 * 40];
  const int tid = threadIdx.x;
  const size_t m0 = (size_t)blockIdx.x * 128;
  const size_t n0 = (size_t)blockIdx.y * 128;
  const int nk = K >> 5;

  // staging: 512 chunks of 16B (128 rows x 32 bf16); 256 threads -> 2 chunks each
  const int c0 = tid, c1 = tid + 256;
  const int r0 = c0 >> 2, kp0 = (c0 & 3) << 3;
  const int r1 = c1 >> 2, kp1 = (c1 & 3) << 3;
  const unsigned short* Ap0 = A + (m0 + r0) * (size_t)K + kp0;
  const unsigned short* Ap1 = A + (m0 + r1) * (size_t)K + kp1;
  const unsigned short* Bp0 = Bt + (n0 + r0) * (size_t)K + kp0;
  const unsigned short* Bp1 = Bt + (n0 + r1) * (size_t)K + kp1;
  const int sa0 = r0 * 40 + kp0, sa1 = r1 * 40 + kp1;

  bf16x8 va0 = *(const bf16x8*)Ap0;
  bf16x8 va1 = *(const bf16x8*)Ap1;
  bf16x8 vb0 = *(const bf16x8*)Bp0;
  bf16x8 vb1 = *(const bf16x8*)Bp1;

  const int wid = tid >> 6, lane = tid & 63;
  const int wr = wid >> 1, wc = wid & 1;
  const int lrow = lane & 15, lg = lane >> 4, lk = lg << 3;
  const int abase = (wr * 64 + lrow) * 40 + lk;
  const int bbase = (wc * 64 + lrow) * 40 + lk;

  const f32x4 zero = {0.f, 0.f, 0.f, 0.f};
  f32x4 acc[4][4];
#pragma unroll
  for (int i = 0; i < 4; ++i)
#pragma unroll
    for (int j = 0; j < 4; ++j) acc[i][j] = zero;

  for (int kt = 0; kt < nk; ++kt) {
    __syncthreads();  // previous readers done
    *(bf16x8*)&As[sa0] = va0;
    *(bf16x8*)&As[sa1] = va1;
    *(bf16x8*)&Bs[sa0] = vb0;
    *(bf16x8*)&Bs[sa1] = vb1;
    __syncthreads();
    if (kt + 1 < nk) {  // prefetch next k-tile into regs; latency hides under MFMA
      const size_t ko = (size_t)(kt + 1) << 5;
      va0 = *(const bf16x8*)(Ap0 + ko);
      va1 = *(const bf16x8*)(Ap1 + ko);
      vb0 = *(const bf16x8*)(Bp0 + ko);
      vb1 = *(const bf16x8*)(Bp1 + ko);
    }
    bf16x8 af[4], bfr[4];
#pragma unroll
    for (int mt = 0; mt < 4; ++mt) af[mt] = *(const bf16x8*)&As[abase + mt * 16 * 40];
#pragma unroll
    for (int nt = 0; nt < 4; ++nt) bfr[nt] = *(const bf16x8*)&Bs[bbase + nt * 16 * 40];
#pragma unroll
    for (int mt = 0; mt < 4; ++mt)
#pragma unroll
      for (int nt = 0; nt < 4; ++nt) acc[mt][nt] = MFMA16(af[mt], bfr[nt], acc[mt][nt]);
  }

#pragma unroll
  for (int mt = 0; mt < 4; ++mt)
#pragma unroll
    for (int nt = 0; nt < 4; ++nt) {
      const size_t col = n0 + wc * 64 + nt * 16 + lrow;
#pragma unroll
      for (int i = 0; i < 4; ++i) {
        const size_t r = m0 + wr * 64 + mt * 16 + lg * 4 + i;
        if constexpr (OUTF32)
          Cf[r * N + col] = acc[mt][nt][i] + bias[col];
        else
          Cb[r * N + col] = f2bf(acc[mt][nt][i]);
      }
    }
}

// ------- fused flash attention: one block = (b,h,g, 64 q rows); 4 waves x 16 rows -------
__global__ __launch_bounds__(256, 2)
void attn_kernel(const unsigned short* __restrict__ qb, const unsigned short* __restrict__ kvb,
                 const unsigned short* __restrict__ vT, unsigned short* __restrict__ ob) {
  __shared__ unsigned short Pw[4][16][72];  // per-wave P tile (16 rows x 64 keys, +8 pad)
  const int tid = threadIdx.x;
  const int wid = tid >> 6, lane = tid & 63;
  const int lrow = lane & 15, lg = lane >> 4, lk = lg << 3;
  const int q0 = blockIdx.x * 64 + wid * 16;
  const int bhg = blockIdx.y;
  const int b = bhg >> 5, h = (bhg >> 2) & 7, g = bhg & 3;

  const unsigned short* qptr = qb + ((size_t)b * Nn + q0) * Dd + h * (Gg * Cc) + g * Cc;
  const unsigned short* kptr = kvb + (size_t)b * Nn * KVW + h * Cc;
  const unsigned short* vptr = vT + (size_t)(b * Hh + h) * Cc * Nn;

  bf16x8 qf[2];
#pragma unroll
  for (int kc = 0; kc < 2; ++kc)
    qf[kc] = *(const bf16x8*)(qptr + (size_t)lrow * Dd + kc * 32 + lk);

  const f32x4 zero = {0.f, 0.f, 0.f, 0.f};
  f32x4 o[4];
  float M_[4], L_[4];
#pragma unroll
  for (int i = 0; i < 4; ++i) { M_[i] = -1e30f; L_[i] = 0.f; }
#pragma unroll
  for (int ct = 0; ct < 4; ++ct) o[ct] = zero;

  for (int s0 = 0; s0 < Nn; s0 += 64) {
    // --- QK^T: 4 key tiles of 16, K-dim = 64 (2 mfma each) ---
    f32x4 S[4] = {zero, zero, zero, zero};
#pragma unroll
    for (int st = 0; st < 4; ++st)
#pragma unroll
      for (int kc = 0; kc < 2; ++kc) {
        bf16x8 kf = *(const bf16x8*)(kptr + (size_t)(s0 + st * 16 + lrow) * KVW + kc * 32 + lk);
        S[st] = MFMA16(qf[kc], kf, S[st]);
      }
    // --- online softmax (rows 4*lg+i live on the 16 lanes sharing lg) ---
    float rs[4] = {0.f, 0.f, 0.f, 0.f};
#pragma unroll
    for (int i = 0; i < 4; ++i) {
      float v = fmaxf(fmaxf(S[0][i], S[1][i]), fmaxf(S[2][i], S[3][i]));
#pragma unroll
      for (int m = 1; m < 16; m <<= 1) v = fmaxf(v, __shfl_xor(v, m));
      float Mn_ = fmaxf(M_[i], v);
      float resc = __expf(M_[i] - Mn_);
      M_[i] = Mn_;
      L_[i] *= resc;
#pragma unroll
      for (int ct = 0; ct < 4; ++ct) o[ct][i] *= resc;
    }
#pragma unroll
    for (int st = 0; st < 4; ++st)
#pragma unroll
      for (int i = 0; i < 4; ++i) {
        float p = __expf(S[st][i] - M_[i]);
        rs[i] += p;
        Pw[wid][lg * 4 + i][st * 16 + lrow] = f2bf(p);
      }
#pragma unroll
    for (int i = 0; i < 4; ++i) {
      float v = rs[i];
#pragma unroll
      for (int m = 1; m < 16; m <<= 1) v += __shfl_xor(v, m);
      L_[i] += v;
    }
    __syncthreads();  // own-wave P writes drained; regions are per-wave
    // --- PV: o[ct] += P(16x64) @ V(64 x 16cols) ---
#pragma unroll
    for (int ct = 0; ct < 4; ++ct)
#pragma unroll
      for (int kc = 0; kc < 2; ++kc) {
        bf16x8 pf = *(const bf16x8*)&Pw[wid][lrow][kc * 32 + lk];
        bf16x8 vf = *(const bf16x8*)(vptr + (size_t)(ct * 16 + lrow) * Nn + s0 + kc * 32 + lk);
        o[ct] = MFMA16(pf, vf, o[ct]);
      }
  }

#pragma unroll
  for (int ct = 0; ct < 4; ++ct)
#pragma unroll
    for (int i = 0; i < 4; ++i) {
      const size_t r = (size_t)b * Nn + q0 + lg * 4 + i;
      ob[r * Dd + h * (Gg * Cc) + g * Cc + ct * 16 + lrow] = f2bf(o[ct][i] / L_[i]);
    }
}

extern "C" void kernel_launch(void* const* d_in, const int* in_sizes, int n_in,
                              void* d_out, int out_size, void* d_ws, size_t ws_size,
                              hipStream_t stream) {
  const float* x   = (const float*)d_in[0];
  const float* Wq  = (const float*)d_in[1];
  const float* Wkv = (const float*)d_in[2];
  const float* Wp  = (const float*)d_in[3];
  const float* bp  = (const float*)d_in[4];
  float* out = (float*)d_out;

  char* ws = (char*)d_ws;
  size_t off = 0;
  auto alloc = [&](size_t bytes) {
    char* p = ws + off;
    off += (bytes + 255) & ~(size_t)255;
    return p;
  };
  unsigned short* xb   = (unsigned short*)alloc((size_t)Bb * Nn * Dd * 2);      // 16 MB
  unsigned short* Wqt  = (unsigned short*)alloc((size_t)Dd * Dd * 2);           // 8 MB
  unsigned short* Wkvt = (unsigned short*)alloc((size_t)KVW * Dd * 2);          // 4 MB
  unsigned short* Wpt  = (unsigned short*)alloc((size_t)Dd * Dd * 2);           // 8 MB
  unsigned short* qbf  = (unsigned short*)alloc((size_t)Bb * Nn * Dd * 2);      // 16 MB
  unsigned short* kvb  = (unsigned short*)alloc((size_t)Bb * Nn * KVW * 2);     // 8 MB
  unsigned short* vT   = (unsigned short*)alloc((size_t)Bb * Hh * Cc * Nn * 2); // 4 MB
  unsigned short* ob   = xb;  // reuse: xb dead after GEMM2

  const int M = Bb * Nn;  // 4096
  const float qscale = 0.17677669529663687f;  // 1/sqrt(32)

  xconv<<<2048, 256, 0, stream>>>(x, xb, (Bb * Nn * Dd) / 4);
  wconv<<<dim3(Dd / 32, Dd / 32), 256, 0, stream>>>(Wq, Wqt, Dd, Dd, qscale);
  wconv<<<dim3(KVW / 32, Dd / 32), 256, 0, stream>>>(Wkv, Wkvt, Dd, KVW, 1.0f);
  wconv<<<dim3(Dd / 32, Dd / 32), 256, 0, stream>>>(Wp, Wpt, Dd, Dd, 1.0f);

  gemm_bt<false><<<dim3(M / 128, Dd / 128), 256, 0, stream>>>(xb, Wqt, qbf, nullptr, nullptr, M, Dd, Dd);
  gemm_bt<false><<<dim3(M / 128, KVW / 128), 256, 0, stream>>>(xb, Wkvt, kvb, nullptr, nullptr, M, KVW, Dd);
  vtrans<<<dim3(Nn / 64, Bb * Hh), 256, 0, stream>>>(kvb, vT);
  attn_kernel<<<dim3(Nn / 64, Bb * Hh * Gg), 256, 0, stream>>>(qbf, kvb, vT, ob);
  gemm_bt<true><<<dim3(M / 128, Dd / 128), 256, 0, stream>>>(ob, Wpt, nullptr, out, bp, M, Dd, Dd);
}

// Round 2
// 609.803 us; speedup vs baseline: 1.0053x; 1.0053x over previous
//
#include <hip/hip_runtime.h>
#include <math.h>

typedef __attribute__((ext_vector_type(8))) __bf16 bf16x8;
typedef __attribute__((ext_vector_type(4))) float f32x4;

#define MFMA16(a, b, c) __builtin_amdgcn_mfma_f32_16x16x32_bf16((a), (b), (c), 0, 0, 0)

static constexpr int Bb  = 2;
static constexpr int Nn  = 2048;
static constexpr int Dd  = 2048;
static constexpr int Hh  = 8;
static constexpr int Gg  = 4;
static constexpr int Cc  = 64;    // head dim
static constexpr int KVW = 1024;  // 2*H*C

__device__ __forceinline__ unsigned short f2bf(float f) {
  unsigned int u = __float_as_uint(f);
  u += 0x7FFFu + ((u >> 16) & 1u);   // RNE
  return (unsigned short)(u >> 16);
}

// ---------------- fp32 -> bf16 convert (vectorized) ----------------
__global__ void xconv(const float* __restrict__ x, unsigned short* __restrict__ xb, int n4) {
  int i = blockIdx.x * blockDim.x + threadIdx.x;
  const int stride = gridDim.x * blockDim.x;
  for (; i < n4; i += stride) {
    float4 v = ((const float4*)x)[i];
    ushort4 o;
    o.x = f2bf(v.x); o.y = f2bf(v.y); o.z = f2bf(v.z); o.w = f2bf(v.w);
    ((ushort4*)xb)[i] = o;
  }
}

// ------- weight convert + transpose: W[K][N] fp32 -> Wt[N][K] bf16, scaled -------
__global__ void wconv(const float* __restrict__ W, unsigned short* __restrict__ Wt,
                      int K, int N, float scale) {
  __shared__ float t[32][33];
  const int n0 = blockIdx.x * 32, k0 = blockIdx.y * 32;
  for (int i = threadIdx.x; i < 1024; i += blockDim.x) {
    int r = i >> 5, c = i & 31;
    t[r][c] = W[(size_t)(k0 + r) * N + n0 + c];
  }
  __syncthreads();
  for (int i = threadIdx.x; i < 1024; i += blockDim.x) {
    int r = i >> 5, c = i & 31;
    Wt[(size_t)(n0 + r) * K + k0 + c] = f2bf(t[c][r] * scale);
  }
}

// ------- V transpose: kvb[b][s][512 + h*64 + c] -> vT[b][h][c][s] -------
__global__ void vtrans(const unsigned short* __restrict__ kvb, unsigned short* __restrict__ vT) {
  __shared__ unsigned short t[64][72];
  const int s0 = blockIdx.x * 64;
  const int b = blockIdx.y >> 3, h = blockIdx.y & 7;
  const unsigned short* src = kvb + ((size_t)b * Nn + s0) * KVW + Hh * Cc + h * Cc;
  for (int i = threadIdx.x; i < 4096; i += blockDim.x) {
    int s = i >> 6, c = i & 63;
    t[s][c] = src[(size_t)s * KVW + c];
  }
  __syncthreads();
  unsigned short* dst = vT + (size_t)(b * Hh + h) * Cc * Nn + s0;
  for (int i = threadIdx.x; i < 4096; i += blockDim.x) {
    int c = i >> 6, s = i & 63;
    dst[(size_t)c * Nn + s] = t[s][c];
  }
}

// ------- GEMM: C[M,N] = A[M,K] @ Bt[N,K]^T ; bf16 in, bf16 or (fp32+bias) out -------
// 128x128 tile, 4 waves (2x2), wave tile 64x64, BK=32, single-buffer LDS w/ reg prefetch.
template <bool OUTF32>
__global__ __launch_bounds__(256, 2)
void gemm_bt(const unsigned short* __restrict__ A, const unsigned short* __restrict__ Bt,
             unsigned short* __restrict__ Cb, float* __restrict__ Cf,
             const float* __restrict__ bias, int M, int N, int K) {
  __shared__ unsigned short As[128 * 40];  // +8 pad per row (bank spread)
  __shared__ unsigned short Bs[128 * 40];
  const int tid = threadIdx.x;
  const size_t m0 = (size_t)blockIdx.x * 128;
  const size_t n0 = (size_t)blockIdx.y * 128;
  const int nk = K >> 5;

  // staging: 512 chunks of 16B (128 rows x 32 bf16); 256 threads -> 2 chunks each
  const int c0 = tid, c1 = tid + 256;
  const int r0 = c0 >> 2, kp0 = (c0 & 3) << 3;
  const int r1 = c1 >> 2, kp1 = (c1 & 3) << 3;
  const unsigned short* Ap0 = A + (m0 + r0) * (size_t)K + kp0;
  const unsigned short* Ap1 = A + (m0 + r1) * (size_t)K + kp1;
  const unsigned short* Bp0 = Bt + (n0 + r0) * (size_t)K + kp0;
  const unsigned short* Bp1 = Bt + (n0 + r1) * (size_t)K + kp1;
  const int sa0 = r0 * 40 + kp0, sa1 = r1 * 40 + kp1;

  bf16x8 va0 = *(const bf16x8*)Ap0;
  bf16x8 va1 = *(const bf16x8*)Ap1;
  bf16x8 vb0 = *(const bf16x8*)Bp0;
  bf16x8 vb1 = *(const bf16x8*)Bp1;

  const int wid = tid >> 6, lane = tid & 63;
  const int wr = wid >> 1, wc = wid & 1;
  const int lrow = lane & 15, lg = lane >> 4, lk = lg << 3;
  const int abase = (wr * 64 + lrow) * 40 + lk;
  const int bbase = (wc * 64 + lrow) * 40 + lk;

  const f32x4 zero = {0.f, 0.f, 0.f, 0.f};
  f32x4 acc[4][4];
#pragma unroll
  for (int i = 0; i < 4; ++i)
#pragma unroll
    for (int j = 0; j < 4; ++j) acc[i][j] = zero;

  for (int kt = 0; kt < nk; ++kt) {
    __syncthreads();  // previous readers done
    *(bf16x8*)&As[sa0] = va0;
    *(bf16x8*)&As[sa1] = va1;
    *(bf16x8*)&Bs[sa0] = vb0;
    *(bf16x8*)&Bs[sa1] = vb1;
    __syncthreads();
    if (kt + 1 < nk) {  // prefetch next k-tile into regs; latency hides under MFMA
      const size_t ko = (size_t)(kt + 1) << 5;
      va0 = *(const bf16x8*)(Ap0 + ko);
      va1 = *(const bf16x8*)(Ap1 + ko);
      vb0 = *(const bf16x8*)(Bp0 + ko);
      vb1 = *(const bf16x8*)(Bp1 + ko);
    }
    bf16x8 af[4], bfr[4];
#pragma unroll
    for (int mt = 0; mt < 4; ++mt) af[mt] = *(const bf16x8*)&As[abase + mt * 16 * 40];
#pragma unroll
    for (int nt = 0; nt < 4; ++nt) bfr[nt] = *(const bf16x8*)&Bs[bbase + nt * 16 * 40];
#pragma unroll
    for (int mt = 0; mt < 4; ++mt)
#pragma unroll
      for (int nt = 0; nt < 4; ++nt) acc[mt][nt] = MFMA16(af[mt], bfr[nt], acc[mt][nt]);
  }

#pragma unroll
  for (int mt = 0; mt < 4; ++mt)
#pragma unroll
    for (int nt = 0; nt < 4; ++nt) {
      const size_t col = n0 + wc * 64 + nt * 16 + lrow;
#pragma unroll
      for (int i = 0; i < 4; ++i) {
        const size_t r = m0 + wr * 64 + mt * 16 + lg * 4 + i;
        if constexpr (OUTF32)
          Cf[r * N + col] = acc[mt][nt][i] + bias[col];
        else
          Cb[r * N + col] = f2bf(acc[mt][nt][i]);
      }
    }
}

// ------- fused flash attention: one block = (b,h,g, 64 q rows); 4 waves x 16 rows -------
// Barrier-free: P tile is per-wave LDS; K frags double-buffered in regs across
// s0-tiles; V frags issued at tile start (used post-softmax, ~400cy later).
// Softmax in exp2 domain (log2e folded into Wq scale).
__global__ __launch_bounds__(256, 2)
void attn_kernel(const unsigned short* __restrict__ qb, const unsigned short* __restrict__ kvb,
                 const unsigned short* __restrict__ vT, unsigned short* __restrict__ ob) {
  __shared__ unsigned short Pw[4][16][72];  // per-wave P tile (16 rows x 64 keys, +8 pad)
  const int tid = threadIdx.x;
  const int wid = tid >> 6, lane = tid & 63;
  const int lrow = lane & 15, lg = lane >> 4, lk = lg << 3;
  const int q0 = blockIdx.x * 64 + wid * 16;
  const int bhg = blockIdx.y;
  const int b = bhg >> 5, h = (bhg >> 2) & 7, g = bhg & 3;

  const unsigned short* qptr = qb + ((size_t)b * Nn + q0) * Dd + h * (Gg * Cc) + g * Cc;
  const unsigned short* kptr = kvb + (size_t)b * Nn * KVW + h * Cc;
  const unsigned short* vptr = vT + (size_t)(b * Hh + h) * Cc * Nn;

  bf16x8 qf[2];
#pragma unroll
  for (int kc = 0; kc < 2; ++kc)
    qf[kc] = *(const bf16x8*)(qptr + (size_t)lrow * Dd + kc * 32 + lk);

  const f32x4 zero = {0.f, 0.f, 0.f, 0.f};
  f32x4 o[4];
  float M_[4], L_[4];
#pragma unroll
  for (int i = 0; i < 4; ++i) { M_[i] = -1e30f; L_[i] = 0.f; }
#pragma unroll
  for (int ct = 0; ct < 4; ++ct) o[ct] = zero;

  auto loadK = [&](bf16x8 (&kf)[4][2], int s0) {
#pragma unroll
    for (int st = 0; st < 4; ++st)
#pragma unroll
      for (int kc = 0; kc < 2; ++kc)
        kf[st][kc] = *(const bf16x8*)(kptr + (size_t)(s0 + st * 16 + lrow) * KVW + kc * 32 + lk);
  };

  auto process = [&](int s0, bf16x8 (&kf)[4][2]) {
    // V prefetch: independent of QK^T/softmax; first consumed after softmax.
    bf16x8 vf[4][2];
#pragma unroll
    for (int ct = 0; ct < 4; ++ct)
#pragma unroll
      for (int kc = 0; kc < 2; ++kc)
        vf[ct][kc] = *(const bf16x8*)(vptr + (size_t)(ct * 16 + lrow) * Nn + s0 + kc * 32 + lk);

    // --- QK^T: S[st] col=lane&15 -> key st*16+lrow, row 4*lg+i -> q-row ---
    f32x4 S[4] = {zero, zero, zero, zero};
#pragma unroll
    for (int st = 0; st < 4; ++st)
#pragma unroll
      for (int kc = 0; kc < 2; ++kc)
        S[st] = MFMA16(qf[kc], kf[st][kc], S[st]);

    // --- online softmax (exp2 domain), rows 4*lg+i across the 16 lanes of lg-group ---
    float rs[4] = {0.f, 0.f, 0.f, 0.f};
#pragma unroll
    for (int i = 0; i < 4; ++i) {
      float v = fmaxf(fmaxf(S[0][i], S[1][i]), fmaxf(S[2][i], S[3][i]));
#pragma unroll
      for (int m = 1; m < 16; m <<= 1) v = fmaxf(v, __shfl_xor(v, m));
      float Mn_ = fmaxf(M_[i], v);
      float resc = exp2f(M_[i] - Mn_);
      M_[i] = Mn_;
      L_[i] *= resc;
#pragma unroll
      for (int ct = 0; ct < 4; ++ct) o[ct][i] *= resc;
    }
#pragma unroll
    for (int st = 0; st < 4; ++st)
#pragma unroll
      for (int i = 0; i < 4; ++i) {
        float p = exp2f(S[st][i] - M_[i]);
        rs[i] += p;
        Pw[wid][lg * 4 + i][st * 16 + lrow] = f2bf(p);
      }
#pragma unroll
    for (int i = 0; i < 4; ++i) {
      float v = rs[i];
#pragma unroll
      for (int m = 1; m < 16; m <<= 1) v += __shfl_xor(v, m);
      L_[i] += v;
    }
    // no barrier: P region is per-wave; compiler inserts lgkmcnt for own writes
    // --- PV: o[ct] += P(16x64) @ V(64 x 16cols) ---
#pragma unroll
    for (int ct = 0; ct < 4; ++ct)
#pragma unroll
      for (int kc = 0; kc < 2; ++kc) {
        bf16x8 pf = *(const bf16x8*)&Pw[wid][lrow][kc * 32 + lk];
        o[ct] = MFMA16(pf, vf[ct][kc], o[ct]);
      }
  };

  bf16x8 kA[4][2], kB[4][2];
  loadK(kA, 0);
  for (int t = 0; t < 32; t += 2) {
    loadK(kB, (t + 1) * 64);          // prefetch next tile's K
    process(t * 64, kA);
    if (t + 2 < 32) loadK(kA, (t + 2) * 64);
    process((t + 1) * 64, kB);
  }

#pragma unroll
  for (int ct = 0; ct < 4; ++ct)
#pragma unroll
    for (int i = 0; i < 4; ++i) {
      const size_t r = (size_t)b * Nn + q0 + lg * 4 + i;
      ob[r * Dd + h * (Gg * Cc) + g * Cc + ct * 16 + lrow] = f2bf(o[ct][i] / L_[i]);
    }
}

extern "C" void kernel_launch(void* const* d_in, const int* in_sizes, int n_in,
                              void* d_out, int out_size, void* d_ws, size_t ws_size,
                              hipStream_t stream) {
  const float* x   = (const float*)d_in[0];
  const float* Wq  = (const float*)d_in[1];
  const float* Wkv = (const float*)d_in[2];
  const float* Wp  = (const float*)d_in[3];
  const float* bp  = (const float*)d_in[4];
  float* out = (float*)d_out;

  char* ws = (char*)d_ws;
  size_t off = 0;
  auto alloc = [&](size_t bytes) {
    char* p = ws + off;
    off += (bytes + 255) & ~(size_t)255;
    return p;
  };
  unsigned short* xb   = (unsigned short*)alloc((size_t)Bb * Nn * Dd * 2);      // 16 MB
  unsigned short* Wqt  = (unsigned short*)alloc((size_t)Dd * Dd * 2);           // 8 MB
  unsigned short* Wkvt = (unsigned short*)alloc((size_t)KVW * Dd * 2);          // 4 MB
  unsigned short* Wpt  = (unsigned short*)alloc((size_t)Dd * Dd * 2);           // 8 MB
  unsigned short* qbf  = (unsigned short*)alloc((size_t)Bb * Nn * Dd * 2);      // 16 MB
  unsigned short* kvb  = (unsigned short*)alloc((size_t)Bb * Nn * KVW * 2);     // 8 MB
  unsigned short* vT   = (unsigned short*)alloc((size_t)Bb * Hh * Cc * Nn * 2); // 4 MB
  unsigned short* ob   = xb;  // reuse: xb dead after GEMM2

  const int M = Bb * Nn;  // 4096
  // 1/sqrt(32) * log2(e): softmax computed in exp2 domain (identical math)
  const float qscale = 0.17677669529663687f * 1.4426950408889634f;

  xconv<<<2048, 256, 0, stream>>>(x, xb, (Bb * Nn * Dd) / 4);
  wconv<<<dim3(Dd / 32, Dd / 32), 256, 0, stream>>>(Wq, Wqt, Dd, Dd, qscale);
  wconv<<<dim3(KVW / 32, Dd / 32), 256, 0, stream>>>(Wkv, Wkvt, Dd, KVW, 1.0f);
  wconv<<<dim3(Dd / 32, Dd / 32), 256, 0, stream>>>(Wp, Wpt, Dd, Dd, 1.0f);

  gemm_bt<false><<<dim3(M / 128, Dd / 128), 256, 0, stream>>>(xb, Wqt, qbf, nullptr, nullptr, M, Dd, Dd);
  gemm_bt<false><<<dim3(M / 128, KVW / 128), 256, 0, stream>>>(xb, Wkvt, kvb, nullptr, nullptr, M, KVW, Dd);
  vtrans<<<dim3(Nn / 64, Bb * Hh), 256, 0, stream>>>(kvb, vT);
  attn_kernel<<<dim3(Nn / 64, Bb * Hh * Gg), 256, 0, stream>>>(qbf, kvb, vT, ob);
  gemm_bt<true><<<dim3(M / 128, Dd / 128), 256, 0, stream>>>(ob, Wpt, nullptr, out, bp, M, Dd, Dd);
}

// Round 3
// 356.739 us; speedup vs baseline: 1.7184x; 1.7094x over previous
//
#include <hip/hip_runtime.h>
#include <math.h>

typedef __attribute__((ext_vector_type(8))) __bf16 bf16x8;
typedef __attribute__((ext_vector_type(4))) float f32x4;

#define MFMA16(a, b, c) __builtin_amdgcn_mfma_f32_16x16x32_bf16((a), (b), (c), 0, 0, 0)

// DPP rotate within 16-lane row (pure VALU cross-lane; all lanes active here)
#define RORF(v, ctrl) __int_as_float(__builtin_amdgcn_mov_dpp(__float_as_int(v), (ctrl), 0xf, 0xf, true))

#define GLOAD_LDS(g, l)                                                                     \
  __builtin_amdgcn_global_load_lds((const __attribute__((address_space(1))) unsigned int*)(g), \
                                   (__attribute__((address_space(3))) unsigned int*)(l), 16, 0, 0)

static constexpr int Bb  = 2;
static constexpr int Nn  = 2048;
static constexpr int Dd  = 2048;
static constexpr int Hh  = 8;
static constexpr int Gg  = 4;
static constexpr int Cc  = 64;    // head dim
static constexpr int KVW = 1024;  // 2*H*C

__device__ __forceinline__ unsigned short f2bf(float f) {
  unsigned int u = __float_as_uint(f);
  u += 0x7FFFu + ((u >> 16) & 1u);   // RNE
  return (unsigned short)(u >> 16);
}

// ---------------- fp32 -> bf16 convert (vectorized) ----------------
__global__ void xconv(const float* __restrict__ x, unsigned short* __restrict__ xb, int n4) {
  int i = blockIdx.x * blockDim.x + threadIdx.x;
  const int stride = gridDim.x * blockDim.x;
  for (; i < n4; i += stride) {
    float4 v = ((const float4*)x)[i];
    ushort4 o;
    o.x = f2bf(v.x); o.y = f2bf(v.y); o.z = f2bf(v.z); o.w = f2bf(v.w);
    ((ushort4*)xb)[i] = o;
  }
}

// ------- weight convert + transpose: W[K][N] fp32 -> Wt[N][K] bf16, scaled -------
__global__ void wconv(const float* __restrict__ W, unsigned short* __restrict__ Wt,
                      int K, int N, float scale) {
  __shared__ float t[32][33];
  const int n0 = blockIdx.x * 32, k0 = blockIdx.y * 32;
  for (int i = threadIdx.x; i < 1024; i += blockDim.x) {
    int r = i >> 5, c = i & 31;
    t[r][c] = W[(size_t)(k0 + r) * N + n0 + c];
  }
  __syncthreads();
  for (int i = threadIdx.x; i < 1024; i += blockDim.x) {
    int r = i >> 5, c = i & 31;
    Wt[(size_t)(n0 + r) * K + k0 + c] = f2bf(t[c][r] * scale);
  }
}

// ------- V transpose: kvb[b][s][512 + h*64 + c] -> vT[b][h][c][s] -------
__global__ void vtrans(const unsigned short* __restrict__ kvb, unsigned short* __restrict__ vT) {
  __shared__ unsigned short t[64][72];
  const int s0 = blockIdx.x * 64;
  const int b = blockIdx.y >> 3, h = blockIdx.y & 7;
  const unsigned short* src = kvb + ((size_t)b * Nn + s0) * KVW + Hh * Cc + h * Cc;
  for (int i = threadIdx.x; i < 4096; i += blockDim.x) {
    int s = i >> 6, c = i & 63;
    t[s][c] = src[(size_t)s * KVW + c];
  }
  __syncthreads();
  unsigned short* dst = vT + (size_t)(b * Hh + h) * Cc * Nn + s0;
  for (int i = threadIdx.x; i < 4096; i += blockDim.x) {
    int c = i >> 6, s = i & 63;
    dst[(size_t)c * Nn + s] = t[s][c];
  }
}

// ------- GEMM: C[M,N] = A[M,K] @ Bt[N,K]^T ; bf16 in, bf16 or (fp32+bias) out -------
template <bool OUTF32>
__global__ __launch_bounds__(256, 2)
void gemm_bt(const unsigned short* __restrict__ A, const unsigned short* __restrict__ Bt,
             unsigned short* __restrict__ Cb, float* __restrict__ Cf,
             const float* __restrict__ bias, int M, int N, int K) {
  __shared__ unsigned short As[128 * 40];
  __shared__ unsigned short Bs[128 * 40];
  const int tid = threadIdx.x;
  const size_t m0 = (size_t)blockIdx.x * 128;
  const size_t n0 = (size_t)blockIdx.y * 128;
  const int nk = K >> 5;

  const int c0 = tid, c1 = tid + 256;
  const int r0 = c0 >> 2, kp0 = (c0 & 3) << 3;
  const int r1 = c1 >> 2, kp1 = (c1 & 3) << 3;
  const unsigned short* Ap0 = A + (m0 + r0) * (size_t)K + kp0;
  const unsigned short* Ap1 = A + (m0 + r1) * (size_t)K + kp1;
  const unsigned short* Bp0 = Bt + (n0 + r0) * (size_t)K + kp0;
  const unsigned short* Bp1 = Bt + (n0 + r1) * (size_t)K + kp1;
  const int sa0 = r0 * 40 + kp0, sa1 = r1 * 40 + kp1;

  bf16x8 va0 = *(const bf16x8*)Ap0;
  bf16x8 va1 = *(const bf16x8*)Ap1;
  bf16x8 vb0 = *(const bf16x8*)Bp0;
  bf16x8 vb1 = *(const bf16x8*)Bp1;

  const int wid = tid >> 6, lane = tid & 63;
  const int wr = wid >> 1, wc = wid & 1;
  const int lrow = lane & 15, lg = lane >> 4, lk = lg << 3;
  const int abase = (wr * 64 + lrow) * 40 + lk;
  const int bbase = (wc * 64 + lrow) * 40 + lk;

  const f32x4 zero = {0.f, 0.f, 0.f, 0.f};
  f32x4 acc[4][4];
#pragma unroll
  for (int i = 0; i < 4; ++i)
#pragma unroll
    for (int j = 0; j < 4; ++j) acc[i][j] = zero;

  for (int kt = 0; kt < nk; ++kt) {
    __syncthreads();
    *(bf16x8*)&As[sa0] = va0;
    *(bf16x8*)&As[sa1] = va1;
    *(bf16x8*)&Bs[sa0] = vb0;
    *(bf16x8*)&Bs[sa1] = vb1;
    __syncthreads();
    if (kt + 1 < nk) {
      const size_t ko = (size_t)(kt + 1) << 5;
      va0 = *(const bf16x8*)(Ap0 + ko);
      va1 = *(const bf16x8*)(Ap1 + ko);
      vb0 = *(const bf16x8*)(Bp0 + ko);
      vb1 = *(const bf16x8*)(Bp1 + ko);
    }
    bf16x8 af[4], bfr[4];
#pragma unroll
    for (int mt = 0; mt < 4; ++mt) af[mt] = *(const bf16x8*)&As[abase + mt * 16 * 40];
#pragma unroll
    for (int nt = 0; nt < 4; ++nt) bfr[nt] = *(const bf16x8*)&Bs[bbase + nt * 16 * 40];
#pragma unroll
    for (int mt = 0; mt < 4; ++mt)
#pragma unroll
      for (int nt = 0; nt < 4; ++nt) acc[mt][nt] = MFMA16(af[mt], bfr[nt], acc[mt][nt]);
  }

#pragma unroll
  for (int mt = 0; mt < 4; ++mt)
#pragma unroll
    for (int nt = 0; nt < 4; ++nt) {
      const size_t col = n0 + wc * 64 + nt * 16 + lrow;
#pragma unroll
      for (int i = 0; i < 4; ++i) {
        const size_t r = m0 + wr * 64 + mt * 16 + lg * 4 + i;
        if constexpr (OUTF32)
          Cf[r * N + col] = acc[mt][nt][i] + bias[col];
        else
          Cb[r * N + col] = f2bf(acc[mt][nt][i]);
      }
    }
}

// ------- fused flash attention -------
// Block = (b,h,g, 64 q-rows), 4 waves x 16 rows. K-tile(64x64) and V^T-tile(64x64)
// staged in LDS once per block via global_load_lds (async, no VGPR), double-buffered,
// one barrier per tile. LDS 16B-slots XOR-swizzled (slot ^= row&7) via pre-swizzled
// global source (rule: linear dest + inverse-swizzled source + swizzled read).
// Softmax reductions via DPP row_ror (VALU) instead of ds_bpermute shuffles.
__global__ __launch_bounds__(256, 2)
void attn_kernel(const unsigned short* __restrict__ qb, const unsigned short* __restrict__ kvb,
                 const unsigned short* __restrict__ vT, unsigned short* __restrict__ ob) {
  __shared__ unsigned short Ks[2][64 * 64];   // [key][c] rows of 128B, swizzled slots
  __shared__ unsigned short Vs[2][64 * 64];   // [c][s]  rows of 128B, swizzled slots
  __shared__ unsigned short Pw[4][16][72];    // per-wave P tile
  const int tid = threadIdx.x;
  const int wid = tid >> 6, lane = tid & 63;
  const int lrow = lane & 15, lg = lane >> 4, lk = lg << 3;
  const int q0 = blockIdx.x * 64 + wid * 16;
  const int bhg = blockIdx.y;
  const int b = bhg >> 5, h = (bhg >> 2) & 7, g = bhg & 3;

  const unsigned short* qptr = qb + ((size_t)b * Nn + q0) * Dd + h * (Gg * Cc) + g * Cc;
  const unsigned short* kptr = kvb + (size_t)b * Nn * KVW + h * Cc;
  const unsigned short* vptr = vT + (size_t)(b * Hh + h) * Cc * Nn;

  // staging geometry: 8 chunks of 1KB each for K and V; wave wid owns chunks {2wid, 2wid+1}.
  // chunk c, lane l -> LDS row c*8+(l>>3), phys slot l&7 (linear dest).
  // content must be logical slot (l&7)^(row&7); row&7 == l>>3 here.
  const int sub = lane >> 3, slot = lane & 7;
  const int gslot = slot ^ sub;
  const int cA = wid * 2, cB = wid * 2 + 1;
  const unsigned short* gk0 = kptr + (size_t)(cA * 8 + sub) * KVW + gslot * 8;
  const unsigned short* gk1 = kptr + (size_t)(cB * 8 + sub) * KVW + gslot * 8;
  const unsigned short* gv0 = vptr + (size_t)(cA * 8 + sub) * Nn + gslot * 8;
  const unsigned short* gv1 = vptr + (size_t)(cB * 8 + sub) * Nn + gslot * 8;

  bf16x8 qf[2];
#pragma unroll
  for (int kc = 0; kc < 2; ++kc)
    qf[kc] = *(const bf16x8*)(qptr + (size_t)lrow * Dd + kc * 32 + lk);

  const f32x4 zero = {0.f, 0.f, 0.f, 0.f};
  f32x4 o[4];
  float M_[4], L_[4];
#pragma unroll
  for (int i = 0; i < 4; ++i) { M_[i] = -1e30f; L_[i] = 0.f; }
#pragma unroll
  for (int ct = 0; ct < 4; ++ct) o[ct] = zero;

  // prologue: stage tile 0 into buf 0
  GLOAD_LDS(gk0, &Ks[0][cA * 512]);
  GLOAD_LDS(gk1, &Ks[0][cB * 512]);
  GLOAD_LDS(gv0, &Vs[0][cA * 512]);
  GLOAD_LDS(gv1, &Vs[0][cB * 512]);
  __syncthreads();

  int buf = 0;
  for (int t = 0; t < Nn / 64; ++t) {
    if (t + 1 < Nn / 64) {  // issue next tile's async loads first (overlap with compute)
      const size_t ks = (size_t)(t + 1) * 64 * KVW;
      const int vs = (t + 1) * 64;
      GLOAD_LDS(gk0 + ks, &Ks[buf ^ 1][cA * 512]);
      GLOAD_LDS(gk1 + ks, &Ks[buf ^ 1][cB * 512]);
      GLOAD_LDS(gv0 + vs, &Vs[buf ^ 1][cA * 512]);
      GLOAD_LDS(gv1 + vs, &Vs[buf ^ 1][cB * 512]);
    }
    const unsigned short* Kb = &Ks[buf][0];
    const unsigned short* Vb = &Vs[buf][0];

    // --- QK^T: S[st] col=lane&15 -> key st*16+lrow, row 4*lg+i -> q-row ---
    f32x4 S[4] = {zero, zero, zero, zero};
#pragma unroll
    for (int st = 0; st < 4; ++st) {
      const int row = st * 16 + lrow;
#pragma unroll
      for (int kc = 0; kc < 2; ++kc) {
        bf16x8 kf = *(const bf16x8*)&Kb[row * 64 + ((((kc << 2) + lg) ^ (lrow & 7)) << 3)];
        S[st] = MFMA16(qf[kc], kf, S[st]);
      }
    }

    // --- online softmax (exp2 domain); reduce group = DPP row (lanes lg*16..lg*16+15) ---
    float rs[4] = {0.f, 0.f, 0.f, 0.f};
#pragma unroll
    for (int i = 0; i < 4; ++i) {
      float v = fmaxf(fmaxf(S[0][i], S[1][i]), fmaxf(S[2][i], S[3][i]));
      v = fmaxf(v, RORF(v, 0x121));
      v = fmaxf(v, RORF(v, 0x122));
      v = fmaxf(v, RORF(v, 0x124));
      v = fmaxf(v, RORF(v, 0x128));
      float Mn_ = fmaxf(M_[i], v);
      float resc = exp2f(M_[i] - Mn_);
      M_[i] = Mn_;
      L_[i] *= resc;
#pragma unroll
      for (int ct = 0; ct < 4; ++ct) o[ct][i] *= resc;
    }
#pragma unroll
    for (int st = 0; st < 4; ++st)
#pragma unroll
      for (int i = 0; i < 4; ++i) {
        float p = exp2f(S[st][i] - M_[i]);
        rs[i] += p;
        Pw[wid][lg * 4 + i][st * 16 + lrow] = f2bf(p);
      }
#pragma unroll
    for (int i = 0; i < 4; ++i) {
      float v = rs[i];
      v += RORF(v, 0x121);
      v += RORF(v, 0x122);
      v += RORF(v, 0x124);
      v += RORF(v, 0x128);
      L_[i] += v;
    }

    // --- PV: o[ct] += P(16x64) @ V^T-cols; V-frag col=ct*16+lrow (c-dim), k=s ---
#pragma unroll
    for (int ct = 0; ct < 4; ++ct) {
      const int vrow = ct * 16 + lrow;
#pragma unroll
      for (int kc = 0; kc < 2; ++kc) {
        bf16x8 pf = *(const bf16x8*)&Pw[wid][lrow][kc * 32 + lk];
        bf16x8 vf = *(const bf16x8*)&Vb[vrow * 64 + ((((kc << 2) + lg) ^ (lrow & 7)) << 3)];
        o[ct] = MFMA16(pf, vf, o[ct]);
      }
    }
    __syncthreads();  // drains staged loads (vmcnt0) + orders buffer reuse
    buf ^= 1;
  }

#pragma unroll
  for (int ct = 0; ct < 4; ++ct)
#pragma unroll
    for (int i = 0; i < 4; ++i) {
      const size_t r = (size_t)b * Nn + q0 + lg * 4 + i;
      ob[r * Dd + h * (Gg * Cc) + g * Cc + ct * 16 + lrow] = f2bf(o[ct][i] / L_[i]);
    }
}

extern "C" void kernel_launch(void* const* d_in, const int* in_sizes, int n_in,
                              void* d_out, int out_size, void* d_ws, size_t ws_size,
                              hipStream_t stream) {
  const float* x   = (const float*)d_in[0];
  const float* Wq  = (const float*)d_in[1];
  const float* Wkv = (const float*)d_in[2];
  const float* Wp  = (const float*)d_in[3];
  const float* bp  = (const float*)d_in[4];
  float* out = (float*)d_out;

  char* ws = (char*)d_ws;
  size_t off = 0;
  auto alloc = [&](size_t bytes) {
    char* p = ws + off;
    off += (bytes + 255) & ~(size_t)255;
    return p;
  };
  unsigned short* xb   = (unsigned short*)alloc((size_t)Bb * Nn * Dd * 2);
  unsigned short* Wqt  = (unsigned short*)alloc((size_t)Dd * Dd * 2);
  unsigned short* Wkvt = (unsigned short*)alloc((size_t)KVW * Dd * 2);
  unsigned short* Wpt  = (unsigned short*)alloc((size_t)Dd * Dd * 2);
  unsigned short* qbf  = (unsigned short*)alloc((size_t)Bb * Nn * Dd * 2);
  unsigned short* kvb  = (unsigned short*)alloc((size_t)Bb * Nn * KVW * 2);
  unsigned short* vT   = (unsigned short*)alloc((size_t)Bb * Hh * Cc * Nn * 2);
  unsigned short* ob   = xb;  // reuse: xb dead after GEMM2

  const int M = Bb * Nn;  // 4096
  // 1/sqrt(32) * log2(e): softmax computed in exp2 domain (identical math)
  const float qscale = 0.17677669529663687f * 1.4426950408889634f;

  xconv<<<2048, 256, 0, stream>>>(x, xb, (Bb * Nn * Dd) / 4);
  wconv<<<dim3(Dd / 32, Dd / 32), 256, 0, stream>>>(Wq, Wqt, Dd, Dd, qscale);
  wconv<<<dim3(KVW / 32, Dd / 32), 256, 0, stream>>>(Wkv, Wkvt, Dd, KVW, 1.0f);
  wconv<<<dim3(Dd / 32, Dd / 32), 256, 0, stream>>>(Wp, Wpt, Dd, Dd, 1.0f);

  gemm_bt<false><<<dim3(M / 128, Dd / 128), 256, 0, stream>>>(xb, Wqt, qbf, nullptr, nullptr, M, Dd, Dd);
  gemm_bt<false><<<dim3(M / 128, KVW / 128), 256, 0, stream>>>(xb, Wkvt, kvb, nullptr, nullptr, M, KVW, Dd);
  vtrans<<<dim3(Nn / 64, Bb * Hh), 256, 0, stream>>>(kvb, vT);
  attn_kernel<<<dim3(Nn / 64, Bb * Hh * Gg), 256, 0, stream>>>(qbf, kvb, vT, ob);
  gemm_bt<true><<<dim3(M / 128, Dd / 128), 256, 0, stream>>>(ob, Wpt, nullptr, out, bp, M, Dd, Dd);
}

// Round 4
// 275.133 us; speedup vs baseline: 2.2280x; 1.2966x over previous
//
#include <hip/hip_runtime.h>
#include <math.h>

typedef __attribute__((ext_vector_type(8))) __bf16 bf16x8;
typedef __attribute__((ext_vector_type(4))) float f32x4;
typedef __attribute__((ext_vector_type(16))) float f32x16;
typedef __attribute__((ext_vector_type(2))) unsigned u32x2;

#define MFMA16(a, b, c) __builtin_amdgcn_mfma_f32_16x16x32_bf16((a), (b), (c), 0, 0, 0)
#define MFMA32(a, b, c) __builtin_amdgcn_mfma_f32_32x32x16_bf16((a), (b), (c), 0, 0, 0)

#define GLOAD_LDS(g, l)                                                                     \
  __builtin_amdgcn_global_load_lds((const __attribute__((address_space(1))) unsigned int*)(g), \
                                   (__attribute__((address_space(3))) unsigned int*)(l), 16, 0, 0)

static constexpr int Bb  = 2;
static constexpr int Nn  = 2048;
static constexpr int Dd  = 2048;
static constexpr int Hh  = 8;
static constexpr int Gg  = 4;
static constexpr int Cc  = 64;    // head dim
static constexpr int KVW = 1024;  // 2*H*C

__device__ __forceinline__ unsigned short f2bf(float f) {
  unsigned int u = __float_as_uint(f);
  u += 0x7FFFu + ((u >> 16) & 1u);   // RNE
  return (unsigned short)(u >> 16);
}

// cross-half (lane ^ 32) combine via v_permlane32_swap (1 VALU op, no LDS)
__device__ __forceinline__ float xhalf_max(float v) {
  u32x2 r = __builtin_amdgcn_permlane32_swap(__float_as_uint(v), __float_as_uint(v), false, false);
  return fmaxf(__uint_as_float(r.x), __uint_as_float(r.y));
}
__device__ __forceinline__ float xhalf_sum(float v) {
  u32x2 r = __builtin_amdgcn_permlane32_swap(__float_as_uint(v), __float_as_uint(v), false, false);
  return __uint_as_float(r.x) + __uint_as_float(r.y);
}

// ---------------- fp32 -> bf16 convert (vectorized) ----------------
__global__ void xconv(const float* __restrict__ x, unsigned short* __restrict__ xb, int n4) {
  int i = blockIdx.x * blockDim.x + threadIdx.x;
  const int stride = gridDim.x * blockDim.x;
  for (; i < n4; i += stride) {
    float4 v = ((const float4*)x)[i];
    ushort4 o;
    o.x = f2bf(v.x); o.y = f2bf(v.y); o.z = f2bf(v.z); o.w = f2bf(v.w);
    ((ushort4*)xb)[i] = o;
  }
}

// ------- weight convert + transpose: W[K][N] fp32 -> Wt[N][K] bf16, scaled -------
__global__ void wconv(const float* __restrict__ W, unsigned short* __restrict__ Wt,
                      int K, int N, float scale) {
  __shared__ float t[32][33];
  const int n0 = blockIdx.x * 32, k0 = blockIdx.y * 32;
  for (int i = threadIdx.x; i < 1024; i += blockDim.x) {
    int r = i >> 5, c = i & 31;
    t[r][c] = W[(size_t)(k0 + r) * N + n0 + c];
  }
  __syncthreads();
  for (int i = threadIdx.x; i < 1024; i += blockDim.x) {
    int r = i >> 5, c = i & 31;
    Wt[(size_t)(n0 + r) * K + k0 + c] = f2bf(t[c][r] * scale);
  }
}

// ------- V transpose: kvb[b][s][512 + h*64 + c] -> vT[b][h][c][s] -------
__global__ void vtrans(const unsigned short* __restrict__ kvb, unsigned short* __restrict__ vT) {
  __shared__ unsigned short t[64][72];
  const int s0 = blockIdx.x * 64;
  const int b = blockIdx.y >> 3, h = blockIdx.y & 7;
  const unsigned short* src = kvb + ((size_t)b * Nn + s0) * KVW + Hh * Cc + h * Cc;
  for (int i = threadIdx.x; i < 4096; i += blockDim.x) {
    int s = i >> 6, c = i & 63;
    t[s][c] = src[(size_t)s * KVW + c];
  }
  __syncthreads();
  unsigned short* dst = vT + (size_t)(b * Hh + h) * Cc * Nn + s0;
  for (int i = threadIdx.x; i < 4096; i += blockDim.x) {
    int c = i >> 6, s = i & 63;
    dst[(size_t)c * Nn + s] = t[s][c];
  }
}

// ------- GEMM: C[M,N] = A[M,K] @ Bt[N,K]^T ; bf16 in, bf16 or (fp32+bias) out -------
template <bool OUTF32>
__global__ __launch_bounds__(256, 2)
void gemm_bt(const unsigned short* __restrict__ A, const unsigned short* __restrict__ Bt,
             unsigned short* __restrict__ Cb, float* __restrict__ Cf,
             const float* __restrict__ bias, int M, int N, int K) {
  __shared__ unsigned short As[128 * 40];
  __shared__ unsigned short Bs[128 * 40];
  const int tid = threadIdx.x;
  const size_t m0 = (size_t)blockIdx.x * 128;
  const size_t n0 = (size_t)blockIdx.y * 128;
  const int nk = K >> 5;

  const int c0 = tid, c1 = tid + 256;
  const int r0 = c0 >> 2, kp0 = (c0 & 3) << 3;
  const int r1 = c1 >> 2, kp1 = (c1 & 3) << 3;
  const unsigned short* Ap0 = A + (m0 + r0) * (size_t)K + kp0;
  const unsigned short* Ap1 = A + (m0 + r1) * (size_t)K + kp1;
  const unsigned short* Bp0 = Bt + (n0 + r0) * (size_t)K + kp0;
  const unsigned short* Bp1 = Bt + (n0 + r1) * (size_t)K + kp1;
  const int sa0 = r0 * 40 + kp0, sa1 = r1 * 40 + kp1;

  bf16x8 va0 = *(const bf16x8*)Ap0;
  bf16x8 va1 = *(const bf16x8*)Ap1;
  bf16x8 vb0 = *(const bf16x8*)Bp0;
  bf16x8 vb1 = *(const bf16x8*)Bp1;

  const int wid = tid >> 6, lane = tid & 63;
  const int wr = wid >> 1, wc = wid & 1;
  const int lrow = lane & 15, lg = lane >> 4, lk = lg << 3;
  const int abase = (wr * 64 + lrow) * 40 + lk;
  const int bbase = (wc * 64 + lrow) * 40 + lk;

  const f32x4 zero = {0.f, 0.f, 0.f, 0.f};
  f32x4 acc[4][4];
#pragma unroll
  for (int i = 0; i < 4; ++i)
#pragma unroll
    for (int j = 0; j < 4; ++j) acc[i][j] = zero;

  for (int kt = 0; kt < nk; ++kt) {
    __syncthreads();
    *(bf16x8*)&As[sa0] = va0;
    *(bf16x8*)&As[sa1] = va1;
    *(bf16x8*)&Bs[sa0] = vb0;
    *(bf16x8*)&Bs[sa1] = vb1;
    __syncthreads();
    if (kt + 1 < nk) {
      const size_t ko = (size_t)(kt + 1) << 5;
      va0 = *(const bf16x8*)(Ap0 + ko);
      va1 = *(const bf16x8*)(Ap1 + ko);
      vb0 = *(const bf16x8*)(Bp0 + ko);
      vb1 = *(const bf16x8*)(Bp1 + ko);
    }
    bf16x8 af[4], bfr[4];
#pragma unroll
    for (int mt = 0; mt < 4; ++mt) af[mt] = *(const bf16x8*)&As[abase + mt * 16 * 40];
#pragma unroll
    for (int nt = 0; nt < 4; ++nt) bfr[nt] = *(const bf16x8*)&Bs[bbase + nt * 16 * 40];
#pragma unroll
    for (int mt = 0; mt < 4; ++mt)
#pragma unroll
      for (int nt = 0; nt < 4; ++nt) acc[mt][nt] = MFMA16(af[mt], bfr[nt], acc[mt][nt]);
  }

#pragma unroll
  for (int mt = 0; mt < 4; ++mt)
#pragma unroll
    for (int nt = 0; nt < 4; ++nt) {
      const size_t col = n0 + wc * 64 + nt * 16 + lrow;
#pragma unroll
      for (int i = 0; i < 4; ++i) {
        const size_t r = m0 + wr * 64 + mt * 16 + lg * 4 + i;
        if constexpr (OUTF32)
          Cf[r * N + col] = acc[mt][nt][i] + bias[col];
        else
          Cb[r * N + col] = f2bf(acc[mt][nt][i]);
      }
    }
}

// ------- fused flash attention, swapped-QK^T 32x32 structure (T12) -------
// Block = (b,h,g, 128 q-rows), 4 waves x 32 q-rows. K(64x64) / V^T(64x64) staged in
// LDS via global_load_lds, double-buffered, XOR-swizzled 16B slots (slot ^= row&7).
// QK^T computed swapped: S = mfma32(K, Q^T) -> lane owns q-col = lane&31; softmax
// row-reduce = 31 local ops + 1 permlane32_swap. P stays in-register: cvt_pk pairs +
// permlane32_swap assemble PV A-frags directly (no P LDS round-trip).
// Defer-max (T13, THR=8 exp2-units): O-rescale only when row-max grows.
__global__ __launch_bounds__(256, 3)
void attn_kernel(const unsigned short* __restrict__ qb, const unsigned short* __restrict__ kvb,
                 const unsigned short* __restrict__ vT, unsigned short* __restrict__ ob) {
  __shared__ unsigned short Ks[2][4096];   // [key 0..63][c 0..63], swizzled 16B slots
  __shared__ unsigned short Vs[2][4096];   // [c 0..63][s 0..63],  swizzled 16B slots
  const int tid = threadIdx.x;
  const int wid = tid >> 6, lane = tid & 63;
  const int r31 = lane & 31, hi = lane >> 5, r7 = r31 & 7;
  const int q0 = blockIdx.x * 128 + wid * 32;
  const int bhg = blockIdx.y;
  const int b = bhg >> 5, h = (bhg >> 2) & 7, g = bhg & 3;

  const unsigned short* kptr = kvb + (size_t)b * Nn * KVW + h * Cc;
  const unsigned short* vptr = vT + (size_t)(b * Hh + h) * Cc * Nn;

  // staging geometry (identical to verified r3 scheme): 8 chunks x 1KB for K and V;
  // wave wid owns chunks {2wid, 2wid+1}. LDS dest linear; source pre-swizzled.
  const int sub = lane >> 3, slot = lane & 7;
  const int gslot = slot ^ sub;
  const int cA = wid * 2, cB = wid * 2 + 1;
  const unsigned short* gk0 = kptr + (size_t)(cA * 8 + sub) * KVW + gslot * 8;
  const unsigned short* gk1 = kptr + (size_t)(cB * 8 + sub) * KVW + gslot * 8;
  const unsigned short* gv0 = vptr + (size_t)(cA * 8 + sub) * Nn + gslot * 8;
  const unsigned short* gv1 = vptr + (size_t)(cB * 8 + sub) * Nn + gslot * 8;

  // Q^T fragments (B-operand): lane holds Q[q0+r31][c = ks*16 + 8*hi + j]
  bf16x8 qf[4];
  {
    const unsigned short* qrow =
        qb + ((size_t)b * Nn + q0 + r31) * Dd + h * (Gg * Cc) + g * Cc + hi * 8;
#pragma unroll
    for (int ks = 0; ks < 4; ++ks) qf[ks] = *(const bf16x8*)(qrow + ks * 16);
  }

  f32x16 O0 = (f32x16)0.0f, O1 = (f32x16)0.0f;
  float M_ = -1e30f, L_ = 0.0f;

  // prologue: stage tile 0 into buf 0
  GLOAD_LDS(gk0, &Ks[0][cA * 512]);
  GLOAD_LDS(gk1, &Ks[0][cB * 512]);
  GLOAD_LDS(gv0, &Vs[0][cA * 512]);
  GLOAD_LDS(gv1, &Vs[0][cB * 512]);
  __syncthreads();

  int buf = 0;
  for (int t = 0; t < Nn / 64; ++t) {
    if (t + 1 < Nn / 64) {  // async-stage next tile; completes under this tile's compute
      const size_t ks = (size_t)(t + 1) * 64 * KVW;
      const int vs = (t + 1) * 64;
      GLOAD_LDS(gk0 + ks, &Ks[buf ^ 1][cA * 512]);
      GLOAD_LDS(gk1 + ks, &Ks[buf ^ 1][cB * 512]);
      GLOAD_LDS(gv0 + vs, &Vs[buf ^ 1][cA * 512]);
      GLOAD_LDS(gv1 + vs, &Vs[buf ^ 1][cB * 512]);
    }
    const char* Kb = (const char*)&Ks[buf][0];
    const char* Vb = (const char*)&Vs[buf][0];

    // --- QK^T swapped: S[kt2] = K-subtile(32 keys) x Q^T -> D[key][q] ---
    f32x16 S0 = (f32x16)0.0f, S1 = (f32x16)0.0f;
#pragma unroll
    for (int ks = 0; ks < 4; ++ks) {
      const int sl = ((2 * ks + hi) ^ r7) << 4;
      bf16x8 k0 = *(const bf16x8*)(Kb + r31 * 128 + sl);
      bf16x8 k1 = *(const bf16x8*)(Kb + (32 + r31) * 128 + sl);
      S0 = MFMA32(k0, qf[ks], S0);
      S1 = MFMA32(k1, qf[ks], S1);
    }

    // --- row max (lane-local 31 ops + 1 permlane swap) ---
    float t8[8];
#pragma unroll
    for (int i = 0; i < 8; ++i) t8[i] = fmaxf(fmaxf(S0[i], S0[i + 8]), fmaxf(S1[i], S1[i + 8]));
#pragma unroll
    for (int i = 0; i < 4; ++i) t8[i] = fmaxf(t8[i], t8[i + 4]);
    float pmax = fmaxf(fmaxf(t8[0], t8[1]), fmaxf(t8[2], t8[3]));
    pmax = xhalf_max(pmax);

    // --- defer-max (T13): rescale only when row-max grows past THR ---
    if (!__all(pmax <= M_ + 8.0f)) {
      float Mn = fmaxf(M_, pmax);
      float resc = exp2f(M_ - Mn);
      M_ = Mn;
      L_ *= resc;
#pragma unroll
      for (int r = 0; r < 16; ++r) {
        float rr = __shfl(resc, (r & 3) + 8 * (r >> 2) + 4 * hi);
        O0[r] *= rr;
        O1[r] *= rr;
      }
    }

    // --- P = exp2(S - M_), packed to bf16 pairs in-register ---
    float rs = 0.0f;
    unsigned pk[16];
#pragma unroll
    for (int kt2 = 0; kt2 < 2; ++kt2)
#pragma unroll
      for (int blk = 0; blk < 4; ++blk)
#pragma unroll
        for (int m = 0; m < 2; ++m) {
          float pa = exp2f((kt2 ? S1[4 * blk + 2 * m] : S0[4 * blk + 2 * m]) - M_);
          float pb = exp2f((kt2 ? S1[4 * blk + 2 * m + 1] : S0[4 * blk + 2 * m + 1]) - M_);
          rs += pa + pb;
          asm("v_cvt_pk_bf16_f32 %0, %1, %2" : "=v"(pk[kt2 * 8 + blk * 2 + m]) : "v"(pa), "v"(pb));
        }
    L_ += xhalf_sum(rs);

    // --- PV: A-frag assembly via permlane32_swap, B = V^T from LDS ---
#pragma unroll
    for (int vs = 0; vs < 4; ++vs) {
      const int base = (vs >> 1) * 8 + (vs & 1) * 4;
      u32x2 rA = __builtin_amdgcn_permlane32_swap(pk[base + 0], pk[base + 2], false, false);
      u32x2 rB = __builtin_amdgcn_permlane32_swap(pk[base + 1], pk[base + 3], false, false);
      union { unsigned u[4]; bf16x8 v; } pf;
      pf.u[0] = rA.x; pf.u[1] = rB.x; pf.u[2] = rA.y; pf.u[3] = rB.y;
      const int sl = ((2 * vs + hi) ^ r7) << 4;
      bf16x8 v0 = *(const bf16x8*)(Vb + r31 * 128 + sl);
      bf16x8 v1 = *(const bf16x8*)(Vb + (32 + r31) * 128 + sl);
      O0 = MFMA32(pf.v, v0, O0);
      O1 = MFMA32(pf.v, v1, O1);
    }
    __syncthreads();  // drains staged loads + orders buffer reuse
    buf ^= 1;
  }

  // --- epilogue: divide by L (redistributed to O layout), write bf16 ---
  float Linv = 1.0f / L_;
  const size_t orow_base = (size_t)b * Nn + q0;
  const int ocol = h * (Gg * Cc) + g * Cc;
#pragma unroll
  for (int r = 0; r < 16; ++r) {
    const int q_r = (r & 3) + 8 * (r >> 2) + 4 * hi;
    float li = __shfl(Linv, q_r);
    const size_t basep = (orow_base + q_r) * Dd + ocol;
    ob[basep + r31] = f2bf(O0[r] * li);
    ob[basep + 32 + r31] = f2bf(O1[r] * li);
  }
}

extern "C" void kernel_launch(void* const* d_in, const int* in_sizes, int n_in,
                              void* d_out, int out_size, void* d_ws, size_t ws_size,
                              hipStream_t stream) {
  const float* x   = (const float*)d_in[0];
  const float* Wq  = (const float*)d_in[1];
  const float* Wkv = (const float*)d_in[2];
  const float* Wp  = (const float*)d_in[3];
  const float* bp  = (const float*)d_in[4];
  float* out = (float*)d_out;

  char* ws = (char*)d_ws;
  size_t off = 0;
  auto alloc = [&](size_t bytes) {
    char* p = ws + off;
    off += (bytes + 255) & ~(size_t)255;
    return p;
  };
  unsigned short* xb   = (unsigned short*)alloc((size_t)Bb * Nn * Dd * 2);
  unsigned short* Wqt  = (unsigned short*)alloc((size_t)Dd * Dd * 2);
  unsigned short* Wkvt = (unsigned short*)alloc((size_t)KVW * Dd * 2);
  unsigned short* Wpt  = (unsigned short*)alloc((size_t)Dd * Dd * 2);
  unsigned short* qbf  = (unsigned short*)alloc((size_t)Bb * Nn * Dd * 2);
  unsigned short* kvb  = (unsigned short*)alloc((size_t)Bb * Nn * KVW * 2);
  unsigned short* vT   = (unsigned short*)alloc((size_t)Bb * Hh * Cc * Nn * 2);
  unsigned short* ob   = xb;  // reuse: xb dead after GEMM2

  const int M = Bb * Nn;  // 4096
  // 1/sqrt(32) * log2(e): softmax computed in exp2 domain (identical math)
  const float qscale = 0.17677669529663687f * 1.4426950408889634f;

  xconv<<<2048, 256, 0, stream>>>(x, xb, (Bb * Nn * Dd) / 4);
  wconv<<<dim3(Dd / 32, Dd / 32), 256, 0, stream>>>(Wq, Wqt, Dd, Dd, qscale);
  wconv<<<dim3(KVW / 32, Dd / 32), 256, 0, stream>>>(Wkv, Wkvt, Dd, KVW, 1.0f);
  wconv<<<dim3(Dd / 32, Dd / 32), 256, 0, stream>>>(Wp, Wpt, Dd, Dd, 1.0f);

  gemm_bt<false><<<dim3(M / 128, Dd / 128), 256, 0, stream>>>(xb, Wqt, qbf, nullptr, nullptr, M, Dd, Dd);
  gemm_bt<false><<<dim3(M / 128, KVW / 128), 256, 0, stream>>>(xb, Wkvt, kvb, nullptr, nullptr, M, KVW, Dd);
  vtrans<<<dim3(Nn / 64, Bb * Hh), 256, 0, stream>>>(kvb, vT);
  attn_kernel<<<dim3(Nn / 128, Bb * Hh * Gg), 256, 0, stream>>>(qbf, kvb, vT, ob);
  gemm_bt<true><<<dim3(M / 128, Dd / 128), 256, 0, stream>>>(ob, Wpt, nullptr, out, bp, M, Dd, Dd);
}